// Round 5
// baseline (226.547 us; speedup 1.0000x reference)
//
#include <hip/hip_runtime.h>
#include <hip/hip_bf16.h>

#define Bd 16
#define Td 1500
#define Dd 512
#define Hd 1024
#define Ld 20
#define Md (Bd*Td)   // 24000 rows

using f32x4  = __attribute__((ext_vector_type(4))) float;
using short8 = __attribute__((ext_vector_type(8))) short;

__device__ __forceinline__ unsigned short f2bf(float f) {
    union { float f; unsigned u; } v; v.f = f;
    unsigned r = v.u + 0x7fffu + ((v.u >> 16) & 1u);   // RNE
    return (unsigned short)(r >> 16);
}
__device__ __forceinline__ float bf2f(unsigned short u) {
    union { unsigned u; float f; } v; v.u = ((unsigned)u) << 16;
    return v.f;
}
__device__ __forceinline__ void gload_lds16(const void* g, void* l) {
    __builtin_amdgcn_global_load_lds(
        (const __attribute__((address_space(1))) unsigned*)g,
        (__attribute__((address_space(3))) unsigned*)l, 16, 0, 0);
}

// ---------------------------------------------------------------------------
// x fp32 -> bf16 (8 elems/thread)
// ---------------------------------------------------------------------------
__global__ __launch_bounds__(256) void cvt_x_kernel(
    const float* __restrict__ in, unsigned short* __restrict__ out)
{
    size_t i = ((size_t)blockIdx.x * 256 + threadIdx.x) * 8;
    float4 v0 = *(const float4*)(in + i);
    float4 v1 = *(const float4*)(in + i + 4);
    union { unsigned short us[8]; int4 v; } p;
    p.us[0] = f2bf(v0.x); p.us[1] = f2bf(v0.y); p.us[2] = f2bf(v0.z); p.us[3] = f2bf(v0.w);
    p.us[4] = f2bf(v1.x); p.us[5] = f2bf(v1.y); p.us[6] = f2bf(v1.z); p.us[7] = f2bf(v1.w);
    *(int4*)(out + i) = p.v;
}

// ---------------------------------------------------------------------------
// W [K][N] fp32 -> WT [N][K] bf16
// ---------------------------------------------------------------------------
__global__ __launch_bounds__(256) void transpose_convert_k(
    const float* __restrict__ W, unsigned short* __restrict__ WT, int K, int N)
{
    __shared__ float tile[32][33];
    int n0 = blockIdx.x * 32, k0 = blockIdx.y * 32;
    int tx = threadIdx.x, ty = threadIdx.y;   // 32 x 8
#pragma unroll
    for (int j = 0; j < 32; j += 8)
        tile[ty + j][tx] = W[(size_t)(k0 + ty + j) * N + n0 + tx];
    __syncthreads();
#pragma unroll
    for (int j = 0; j < 32; j += 8)
        WT[(size_t)(n0 + ty + j) * K + k0 + tx] = f2bf(tile[tx][ty + j]);
}

// ---------------------------------------------------------------------------
// waT[32][512] bf16: waT[c][d] = wa[d][c] (c<20), else 0
// ---------------------------------------------------------------------------
__global__ __launch_bounds__(256) void prep_waT_kernel(
    const float* __restrict__ wa, unsigned short* __restrict__ waT)
{
    int i = blockIdx.x * 256 + threadIdx.x;   // 0..16383
    int c = i >> 9, d = i & 511;
    waT[i] = (c < Ld) ? f2bf(wa[(size_t)d * Ld + c]) : (unsigned short)0;
}

// ---------------------------------------------------------------------------
// C[M][N] = act(A[M][K] @ BT[N][K]^T + bias)   A,BT,C bf16
// BM=BN=128, BK=32, 4 waves (2x2 of 64x64), mfma 16x16x32 bf16
// Ring-3 LDS pipeline, counted vmcnt(4) (T4) — never drained in-loop.
// XOR k-slot swizzle on gload_lds source + ds_read offset (both-sides).
// Epilogue: C tile staged in LDS (XOR 16B-slot swizzle), coalesced b128 out.
// ---------------------------------------------------------------------------
template<bool RELU_BIAS>
__global__ __launch_bounds__(256) void gemm_lds(
    const unsigned short* __restrict__ A, const unsigned short* __restrict__ BT,
    const float* __restrict__ bias, unsigned short* __restrict__ C,
    int Mdim, int Ndim, int Kdim)
{
    __shared__ __align__(16) unsigned short SH[2][3][128 * 32];  // A/B x ring3, 48KB

    const int tid  = threadIdx.x;
    const int lane = tid & 63;
    const int wave = tid >> 6;
    const int wr   = wave >> 1, wc = wave & 1;

    // chunked XCD swizzle (nwg % 8 == 0 for both GEMMs)
    const int nx  = gridDim.x;
    const int nwg = nx * gridDim.y;
    const int id  = blockIdx.y * nx + blockIdx.x;
    const int nid = (id & 7) * (nwg >> 3) + (id >> 3);
    const int m0  = (nid / nx) * 128;
    const int n0  = (nid % nx) * 128;

    // staging: thread covers (row = tid>>2, 16B k-slot = inverse-swizzled tid&3)
    const int srow  = tid >> 2;                       // 0..63
    const int sslot = (tid & 3) ^ ((tid >> 3) & 3);
    int ar0 = m0 + srow;      if (ar0 >= Mdim) ar0 = Mdim - 1;
    int ar1 = m0 + 64 + srow; if (ar1 >= Mdim) ar1 = Mdim - 1;
    const unsigned short* a0p = A  + (size_t)ar0 * Kdim + sslot * 8;
    const unsigned short* a1p = A  + (size_t)ar1 * Kdim + sslot * 8;
    const unsigned short* b0p = BT + (size_t)(n0 + srow) * Kdim + sslot * 8;
    const unsigned short* b1p = BT + (size_t)(n0 + 64 + srow) * Kdim + sslot * 8;

    const int rsel = lane & 15;
    const int koff = ((lane >> 4) ^ ((lane >> 1) & 3)) * 8;   // swizzled read slot

    f32x4 acc[4][4] = {};
    const int NT = Kdim >> 5;

    auto stage = [&](int t, int b) {
        const int kk = t * 32;
        gload_lds16(a0p + kk, &SH[0][b][wave * 512]);
        gload_lds16(a1p + kk, &SH[0][b][2048 + wave * 512]);
        gload_lds16(b0p + kk, &SH[1][b][wave * 512]);
        gload_lds16(b1p + kk, &SH[1][b][2048 + wave * 512]);
    };

    stage(0, 0);
    stage(1, 1);

    int buf = 0;
    for (int t = 0; t < NT; ++t) {
        if (t + 1 < NT) asm volatile("s_waitcnt vmcnt(4)" ::: "memory");
        else            asm volatile("s_waitcnt vmcnt(0)" ::: "memory");
        __builtin_amdgcn_s_barrier();
        asm volatile("" ::: "memory");

        if (t + 2 < NT) {            // overwrites buf[(t-1)%3]: all reads of it
            int nb = buf + 2;        // finished before barrier above (lockstep)
            if (nb >= 3) nb -= 3;
            stage(t + 2, nb);
        }

        const unsigned short* as = &SH[0][buf][0];
        const unsigned short* bs = &SH[1][buf][0];
        short8 af[4], bfr[4];
#pragma unroll
        for (int m = 0; m < 4; ++m)
            af[m] = *(const short8*)&as[(wr * 64 + m * 16 + rsel) * 32 + koff];
#pragma unroll
        for (int n = 0; n < 4; ++n)
            bfr[n] = *(const short8*)&bs[(wc * 64 + n * 16 + rsel) * 32 + koff];

        __builtin_amdgcn_s_setprio(1);
#pragma unroll
        for (int m = 0; m < 4; ++m)
#pragma unroll
            for (int n = 0; n < 4; ++n)
                acc[m][n] = __builtin_amdgcn_mfma_f32_16x16x32_bf16(af[m], bfr[n], acc[m][n], 0, 0, 0);
        __builtin_amdgcn_s_setprio(0);

        ++buf; if (buf == 3) buf = 0;
    }

    // ---- epilogue: stage C tile in LDS (swizzled), then coalesced write ----
    __syncthreads();                       // loop fully done; reuse SH as Cs
    unsigned short* Cs = (unsigned short*)SH;   // 128x128 ushort = 32KB

    const int rB = wr * 64 + ((lane >> 4) << 2);
    const int cB = wc * 64;
#pragma unroll
    for (int n = 0; n < 4; ++n) {
        const int col = cB + n * 16 + rsel;
        float bvs = 0.f;
        if (RELU_BIAS) bvs = bias[n0 + col];
        const int s = col >> 3, e = col & 7;
#pragma unroll
        for (int m = 0; m < 4; ++m) {
#pragma unroll
            for (int j = 0; j < 4; ++j) {
                const int r = rB + m * 16 + j;
                float v = acc[m][n][j];
                if (RELU_BIAS) v = fmaxf(v + bvs, 0.f);
                Cs[r * 128 + ((s ^ (r & 7)) << 3) + e] = f2bf(v);
            }
        }
    }
    __syncthreads();

    const int row = tid >> 1;
    const int c0  = (tid & 1) * 64;
    const int gr  = m0 + row;
    if (gr < Mdim) {
#pragma unroll
        for (int i = 0; i < 8; ++i) {
            const int s = (c0 >> 3) + i;
            int4 v = *(const int4*)&Cs[row * 128 + ((s ^ (row & 7)) << 3)];
            *(int4*)&C[(size_t)gr * Ndim + n0 + c0 + i * 8] = v;
        }
    }
}

// ---------------------------------------------------------------------------
// att[row][l] = softmax_l( xb[row,:] @ waT[l,:]^T )  via MFMA
// 64 rows/block (wave owns 16 rows), 375 blocks; waT staged whole;
// A ring-3 with counted vmcnt(1).
// ---------------------------------------------------------------------------
__global__ __launch_bounds__(256) void att_mfma_kernel(
    const unsigned short* __restrict__ xb, const unsigned short* __restrict__ waT,
    float* __restrict__ att)
{
    __shared__ __align__(16) unsigned short waTs[16 * 1024];  // 32KB
    __shared__ __align__(16) unsigned short As[3][64 * 32];   // 12KB ring
    __shared__ float sS[64][21];                              // 5.25KB

    const int tid  = threadIdx.x;
    const int lane = tid & 63;
    const int wave = tid >> 6;
    const int m0   = blockIdx.x * 64;

    // stage waTs: dest linear-tiled [kt][c][slot'], source slot = slot'^sigma(c)
    for (int i = tid; i < 2048; i += 256) {
        const int off = i * 8;
        const int kt = off >> 10, c = (off >> 5) & 31, sl = (off >> 3) & 3;
        const int ssl = sl ^ ((c >> 1) & 3);
        *(short8*)&waTs[off] = *(const short8*)&waT[(size_t)c * Dd + kt * 32 + ssl * 8];
    }
    __syncthreads();

    const int srow  = tid >> 2;                      // 0..63
    const int sslot = (tid & 3) ^ ((tid >> 3) & 3);
    const unsigned short* a0p = xb + (size_t)(m0 + srow) * Dd + sslot * 8;

    const int rsel = lane & 15;
    const int koff = ((lane >> 4) ^ ((lane >> 1) & 3)) * 8;

    f32x4 acc[2] = {};

    gload_lds16(a0p, &As[0][wave * 512]);
    gload_lds16(a0p + 32, &As[1][wave * 512]);

    int buf = 0;
    for (int t = 0; t < 16; ++t) {
        if (t < 15) asm volatile("s_waitcnt vmcnt(1)" ::: "memory");
        else        asm volatile("s_waitcnt vmcnt(0)" ::: "memory");
        __builtin_amdgcn_s_barrier();
        asm volatile("" ::: "memory");

        if (t + 2 < 16) {
            int nb = buf + 2; if (nb >= 3) nb -= 3;
            gload_lds16(a0p + (t + 2) * 32, &As[nb][wave * 512]);
        }

        short8 af = *(const short8*)&As[buf][(wave * 16 + rsel) * 32 + koff];
        short8 b0 = *(const short8*)&waTs[t * 1024 + (rsel) * 32 + koff];
        short8 b1 = *(const short8*)&waTs[t * 1024 + (16 + rsel) * 32 + koff];
        acc[0] = __builtin_amdgcn_mfma_f32_16x16x32_bf16(af, b0, acc[0], 0, 0, 0);
        acc[1] = __builtin_amdgcn_mfma_f32_16x16x32_bf16(af, b1, acc[1], 0, 0, 0);

        ++buf; if (buf == 3) buf = 0;
    }

    // logits -> LDS: row = wave*16 + (lane>>4)*4 + j, col = n*16 + rsel
    const int r0 = wave * 16 + ((lane >> 4) << 2);
#pragma unroll
    for (int n = 0; n < 2; ++n) {
        const int c = n * 16 + rsel;
        if (c < 21) {
#pragma unroll
            for (int j = 0; j < 4; ++j)
                sS[r0 + j][c] = acc[n][j];
        }
    }
    __syncthreads();

    if (tid < 64) {
        float mx = -1e30f;
#pragma unroll
        for (int l = 0; l < Ld; ++l) mx = fmaxf(mx, sS[tid][l]);
        float e[Ld]; float sum = 0.f;
#pragma unroll
        for (int l = 0; l < Ld; ++l) { e[l] = __expf(sS[tid][l] - mx); sum += e[l]; }
        const float inv = 1.f / sum;
        const int grow = m0 + tid;
#pragma unroll
        for (int l = 0; l < Ld; ++l)
            att[(size_t)grow * Ld + l] = e[l] * inv;
    }
}

// ---------------------------------------------------------------------------
// out[row][d] = x[row][d] + sum_i att[row][i] * p1[row-i][d]
// 8 rows/block (wave per row); XCD-chunked so each XCD's p1 window fits L2.
// ---------------------------------------------------------------------------
__global__ __launch_bounds__(512) void out_kernel(
    const float* __restrict__ x, const unsigned short* __restrict__ p1,
    const float* __restrict__ att, float* __restrict__ out)
{
    const int bid = blockIdx.x;                       // 3000
    const int nid = (bid & 7) * 375 + (bid >> 3);     // XCD-contiguous chunks
    const int wave = threadIdx.x >> 6;
    const int lane = threadIdx.x & 63;
    const int row  = nid * 8 + wave;
    const int t    = row % Td;
    const int d0   = lane * 8;

    float av[Ld];
    const float* ar = att + (size_t)row * Ld;
#pragma unroll
    for (int i = 0; i < Ld; i += 4) {
        float4 v = *(const float4*)(ar + i);
        av[i] = v.x; av[i + 1] = v.y; av[i + 2] = v.z; av[i + 3] = v.w;
    }

    const float* xr = x + (size_t)row * Dd + d0;
    float4 xa = *(const float4*)xr;
    float4 xb4 = *(const float4*)(xr + 4);
    float acc[8] = { xa.x, xa.y, xa.z, xa.w, xb4.x, xb4.y, xb4.z, xb4.w };

    const int imax = (t < Ld - 1) ? t : (Ld - 1);
    const unsigned short* pr = p1 + (size_t)row * Dd + d0;
    for (int i = 0; i <= imax; ++i) {
        const float a = av[i];
        short8 p = *(const short8*)(pr - (size_t)i * Dd);
#pragma unroll
        for (int j = 0; j < 8; ++j) acc[j] += a * bf2f((unsigned short)p[j]);
    }
    float* orow = out + (size_t)row * Dd + d0;
    float4 o0 = { acc[0], acc[1], acc[2], acc[3] };
    float4 o1 = { acc[4], acc[5], acc[6], acc[7] };
    *(float4*)orow       = o0;
    *(float4*)(orow + 4) = o1;
}

// ---------------------------------------------------------------------------
extern "C" void kernel_launch(void* const* d_in, const int* in_sizes, int n_in,
                              void* d_out, int out_size, void* d_ws, size_t ws_size,
                              hipStream_t stream)
{
    const float* x  = (const float*)d_in[0];
    const float* w1 = (const float*)d_in[1];
    const float* b1 = (const float*)d_in[2];
    const float* wp = (const float*)d_in[3];
    const float* wa = (const float*)d_in[4];
    float* out = (float*)d_out;

    char* ws = (char*)d_ws;
    unsigned short* xb  = (unsigned short*)ws;  ws += (size_t)Md * Dd * 2;   // bf16 x
    unsigned short* w1T = (unsigned short*)ws;  ws += (size_t)Hd * Dd * 2;
    unsigned short* wpT = (unsigned short*)ws;  ws += (size_t)Dd * Hd * 2;
    unsigned short* waT = (unsigned short*)ws;  ws += (size_t)32 * Dd * 2;
    unsigned short* f1  = (unsigned short*)ws;  ws += (size_t)Md * Hd * 2;
    unsigned short* p1  = (unsigned short*)ws;  ws += (size_t)Md * Dd * 2;
    float*          att = (float*)ws;           ws += (size_t)Md * Ld * 4;

    cvt_x_kernel<<<(Md * Dd) / 2048, 256, 0, stream>>>(x, xb);
    transpose_convert_k<<<dim3(Hd / 32, Dd / 32), dim3(32, 8), 0, stream>>>(w1, w1T, Dd, Hd);
    transpose_convert_k<<<dim3(Dd / 32, Hd / 32), dim3(32, 8), 0, stream>>>(wp, wpT, Hd, Dd);
    prep_waT_kernel<<<(32 * Dd) / 256, 256, 0, stream>>>(wa, waT);

    att_mfma_kernel<<<Md / 64, 256, 0, stream>>>(xb, waT, att);

    const int mtiles = (Md + 127) / 128;   // 188
    gemm_lds<true ><<<dim3(Hd / 128, mtiles), 256, 0, stream>>>(xb, w1T, b1, f1, Md, Hd, Dd);
    gemm_lds<false><<<dim3(Dd / 128, mtiles), 256, 0, stream>>>(f1, wpT, nullptr, p1, Md, Dd, Hd);

    out_kernel<<<Md / 8, 512, 0, stream>>>(x, p1, att, out);
}

// Round 6
// 216.252 us; speedup vs baseline: 1.0476x; 1.0476x over previous
//
#include <hip/hip_runtime.h>
#include <hip/hip_bf16.h>

#define Bd 16
#define Td 1500
#define Dd 512
#define Hd 1024
#define Ld 20
#define Md (Bd*Td)   // 24000 rows

using f32x4  = __attribute__((ext_vector_type(4))) float;
using short8 = __attribute__((ext_vector_type(8))) short;

__device__ __forceinline__ unsigned short f2bf(float f) {
    union { float f; unsigned u; } v; v.f = f;
    unsigned r = v.u + 0x7fffu + ((v.u >> 16) & 1u);   // RNE
    return (unsigned short)(r >> 16);
}
__device__ __forceinline__ float bf2f(unsigned short u) {
    union { unsigned u; float f; } v; v.u = ((unsigned)u) << 16;
    return v.f;
}
__device__ __forceinline__ void gload_lds16(const void* g, void* l) {
    __builtin_amdgcn_global_load_lds(
        (const __attribute__((address_space(1))) unsigned*)g,
        (__attribute__((address_space(3))) unsigned*)l, 16, 0, 0);
}

// ---------------------------------------------------------------------------
// Fused prep: [0,6000) x->bf16 | [6000,6512) w1 T | [6512,7024) wp T |
// [7024,7088) waT build.  One launch instead of four.
// ---------------------------------------------------------------------------
__device__ __forceinline__ void transpose_body(
    const float* __restrict__ W, unsigned short* __restrict__ WT,
    int K, int N, int n0, int k0, int tid, float (*tile)[33])
{
    const int tx = tid & 31, ty = tid >> 5;   // 32 x 8
#pragma unroll
    for (int j = 0; j < 32; j += 8)
        tile[ty + j][tx] = W[(size_t)(k0 + ty + j) * N + n0 + tx];
    __syncthreads();
#pragma unroll
    for (int j = 0; j < 32; j += 8)
        WT[(size_t)(n0 + ty + j) * K + k0 + tx] = f2bf(tile[tx][ty + j]);
}

__global__ __launch_bounds__(256) void prep_kernel(
    const float* __restrict__ x,  const float* __restrict__ w1,
    const float* __restrict__ wp, const float* __restrict__ wa,
    unsigned short* __restrict__ xb,  unsigned short* __restrict__ w1T,
    unsigned short* __restrict__ wpT, unsigned short* __restrict__ waT)
{
    __shared__ float tile[32][33];
    const int b = blockIdx.x, tid = threadIdx.x;
    if (b < 6000) {                         // x fp32 -> bf16, 8/thread
        size_t i = ((size_t)b * 256 + tid) * 8;
        float4 v0 = *(const float4*)(x + i);
        float4 v1 = *(const float4*)(x + i + 4);
        union { unsigned short us[8]; int4 v; } p;
        p.us[0] = f2bf(v0.x); p.us[1] = f2bf(v0.y); p.us[2] = f2bf(v0.z); p.us[3] = f2bf(v0.w);
        p.us[4] = f2bf(v1.x); p.us[5] = f2bf(v1.y); p.us[6] = f2bf(v1.z); p.us[7] = f2bf(v1.w);
        *(int4*)(xb + i) = p.v;
    } else if (b < 6512) {                  // w1 [512][1024] -> w1T [1024][512]
        const int idx = b - 6000;           // nx = 1024/32 = 32
        transpose_body(w1, w1T, Dd, Hd, (idx & 31) * 32, (idx >> 5) * 32, tid, tile);
    } else if (b < 7024) {                  // wp [1024][512] -> wpT [512][1024]
        const int idx = b - 6512;           // nx = 512/32 = 16
        transpose_body(wp, wpT, Hd, Dd, (idx & 15) * 32, (idx >> 4) * 32, tid, tile);
    } else {                                // waT[32][512]: wa[d][c] (c<20) else 0
        const int i = (b - 7024) * 256 + tid;   // 0..16383
        const int c = i >> 9, d = i & 511;
        waT[i] = (c < Ld) ? f2bf(wa[(size_t)d * Ld + c]) : (unsigned short)0;
    }
}

// ---------------------------------------------------------------------------
// C[M][N] = act(A[M][K] @ BT[N][K]^T + bias)   A,BT,C bf16
// BM=256 BN=128 BK=32, 8 waves (4x2 of 64x64), mfma 16x16x32 bf16
// Ring-3 LDS (A 3x16KB + B 3x8KB = 72KB) -> 2 blocks/CU = 16 waves/CU.
// Counted vmcnt(3) (3 gloads/wave/stage) — never drained in-loop.
// XOR k-slot swizzle on gload source + ds_read (both-sides involution).
// Epilogue: C staged in LDS (swizzled slots), coalesced b128 write-out.
// ---------------------------------------------------------------------------
template<bool RELU_BIAS>
__global__ __launch_bounds__(512) void gemm_lds(
    const unsigned short* __restrict__ A, const unsigned short* __restrict__ BT,
    const float* __restrict__ bias, unsigned short* __restrict__ C,
    int Mdim, int Ndim, int Kdim)
{
    // A bufs: [0, 3*8192), B bufs: [24576, 24576 + 3*4096)  (ushorts)
    __shared__ __align__(16) unsigned short SH[3 * 8192 + 3 * 4096];  // 73.7KB

    const int tid  = threadIdx.x;
    const int lane = tid & 63;
    const int wave = tid >> 6;
    const int wr   = wave >> 1, wc = wave & 1;   // 4 x 2 of 64x64

    // chunked XCD swizzle (nwg % 8 == 0: 752 and 376)
    const int nx  = gridDim.x;
    const int nwg = nx * gridDim.y;
    const int id  = blockIdx.y * nx + blockIdx.x;
    const int nid = (id & 7) * (nwg >> 3) + (id >> 3);
    const int m0  = (nid / nx) * 256;
    const int n0  = (nid % nx) * 128;

    // staging: thread -> (row = tid>>2 in 0..127, 16B slot = tid&3, swizzled src)
    const int srow  = tid >> 2;
    const int sslot = (tid & 3) ^ ((srow >> 1) & 3);   // sig(row+128)==sig(row)
    int aR0 = m0 + srow;       if (aR0 >= Mdim) aR0 = Mdim - 1;
    int aR1 = m0 + 128 + srow; if (aR1 >= Mdim) aR1 = Mdim - 1;
    const unsigned short* a0p = A  + (size_t)aR0 * Kdim + sslot * 8;
    const unsigned short* a1p = A  + (size_t)aR1 * Kdim + sslot * 8;
    const unsigned short* b0p = BT + (size_t)(n0 + srow) * Kdim + sslot * 8;

    const int rsel = lane & 15;
    const int koff = ((lane >> 4) ^ ((lane >> 1) & 3)) * 8;   // swizzled read slot

    f32x4 acc[4][4] = {};
    const int NT = Kdim >> 5;

    auto stage = [&](int t, int b) {
        const int kk = t * 32;
        gload_lds16(a0p + kk, SH + b * 8192 + wave * 512);           // rows 0..127
        gload_lds16(a1p + kk, SH + b * 8192 + 4096 + wave * 512);    // rows 128..255
        gload_lds16(b0p + kk, SH + 24576 + b * 4096 + wave * 512);   // B rows 0..127
    };

    stage(0, 0);
    stage(1, 1);

    int buf = 0;
    for (int t = 0; t < NT; ++t) {
        if (t + 1 < NT) asm volatile("s_waitcnt vmcnt(3)" ::: "memory");
        else            asm volatile("s_waitcnt vmcnt(0)" ::: "memory");
        __builtin_amdgcn_s_barrier();
        asm volatile("" ::: "memory");

        if (t + 2 < NT) {            // overwrites buf[(t-1)%3]: reads done pre-barrier
            int nb = buf + 2; if (nb >= 3) nb -= 3;
            stage(t + 2, nb);
        }

        const unsigned short* as = SH + buf * 8192;
        const unsigned short* bs = SH + 24576 + buf * 4096;
        short8 af[4], bfr[4];
#pragma unroll
        for (int m = 0; m < 4; ++m)
            af[m] = *(const short8*)&as[(wr * 64 + m * 16 + rsel) * 32 + koff];
#pragma unroll
        for (int n = 0; n < 4; ++n)
            bfr[n] = *(const short8*)&bs[(wc * 64 + n * 16 + rsel) * 32 + koff];

        __builtin_amdgcn_s_setprio(1);
#pragma unroll
        for (int m = 0; m < 4; ++m)
#pragma unroll
            for (int n = 0; n < 4; ++n)
                acc[m][n] = __builtin_amdgcn_mfma_f32_16x16x32_bf16(af[m], bfr[n], acc[m][n], 0, 0, 0);
        __builtin_amdgcn_s_setprio(0);

        ++buf; if (buf == 3) buf = 0;
    }

    // ---- epilogue: stage C tile (256x128) in LDS swizzled, coalesced out ----
    __syncthreads();
    unsigned short* Cs = SH;                // 256*128 ushort = 64KB <= 73.7KB

    const int rB = wr * 64 + ((lane >> 4) << 2);
    const int cB = wc * 64;
#pragma unroll
    for (int n = 0; n < 4; ++n) {
        const int col = cB + n * 16 + rsel;
        float bvs = 0.f;
        if (RELU_BIAS) bvs = bias[n0 + col];
        const int s = col >> 3, e = col & 7;
#pragma unroll
        for (int m = 0; m < 4; ++m) {
#pragma unroll
            for (int j = 0; j < 4; ++j) {
                const int r = rB + m * 16 + j;
                float v = acc[m][n][j];
                if (RELU_BIAS) v = fmaxf(v + bvs, 0.f);
                Cs[r * 128 + ((s ^ (r & 7)) << 3) + e] = f2bf(v);
            }
        }
    }
    __syncthreads();

    const int row = tid >> 1;               // 0..255
    const int c0  = (tid & 1) * 64;
    const int gr  = m0 + row;
    if (gr < Mdim) {
#pragma unroll
        for (int i = 0; i < 8; ++i) {
            const int s = (c0 >> 3) + i;
            int4 v = *(const int4*)&Cs[row * 128 + ((s ^ (row & 7)) << 3)];
            *(int4*)&C[(size_t)gr * Ndim + n0 + c0 + i * 8] = v;
        }
    }
}

// ---------------------------------------------------------------------------
// att[row][l] = softmax_l( xb[row,:] @ waT[l,:]^T )  via MFMA
// 64 rows/block (wave owns 16 rows), 375 blocks; waT staged whole;
// A ring-3 with counted vmcnt(1).
// ---------------------------------------------------------------------------
__global__ __launch_bounds__(256) void att_mfma_kernel(
    const unsigned short* __restrict__ xb, const unsigned short* __restrict__ waT,
    float* __restrict__ att)
{
    __shared__ __align__(16) unsigned short waTs[16 * 1024];  // 32KB
    __shared__ __align__(16) unsigned short As[3][64 * 32];   // 12KB ring
    __shared__ float sS[64][21];                              // 5.25KB

    const int tid  = threadIdx.x;
    const int lane = tid & 63;
    const int wave = tid >> 6;
    const int m0   = blockIdx.x * 64;

    // stage waTs: dest linear-tiled [kt][c][slot'], source slot = slot'^sigma(c)
    for (int i = tid; i < 2048; i += 256) {
        const int off = i * 8;
        const int kt = off >> 10, c = (off >> 5) & 31, sl = (off >> 3) & 3;
        const int ssl = sl ^ ((c >> 1) & 3);
        *(short8*)&waTs[off] = *(const short8*)&waT[(size_t)c * Dd + kt * 32 + ssl * 8];
    }
    __syncthreads();

    const int srow  = tid >> 2;                      // 0..63
    const int sslot = (tid & 3) ^ ((tid >> 3) & 3);
    const unsigned short* a0p = xb + (size_t)(m0 + srow) * Dd + sslot * 8;

    const int rsel = lane & 15;
    const int koff = ((lane >> 4) ^ ((lane >> 1) & 3)) * 8;

    f32x4 acc[2] = {};

    gload_lds16(a0p, &As[0][wave * 512]);
    gload_lds16(a0p + 32, &As[1][wave * 512]);

    int buf = 0;
    for (int t = 0; t < 16; ++t) {
        if (t < 15) asm volatile("s_waitcnt vmcnt(1)" ::: "memory");
        else        asm volatile("s_waitcnt vmcnt(0)" ::: "memory");
        __builtin_amdgcn_s_barrier();
        asm volatile("" ::: "memory");

        if (t + 2 < 16) {
            int nb = buf + 2; if (nb >= 3) nb -= 3;
            gload_lds16(a0p + (t + 2) * 32, &As[nb][wave * 512]);
        }

        short8 af = *(const short8*)&As[buf][(wave * 16 + rsel) * 32 + koff];
        short8 b0 = *(const short8*)&waTs[t * 1024 + (rsel) * 32 + koff];
        short8 b1 = *(const short8*)&waTs[t * 1024 + (16 + rsel) * 32 + koff];
        acc[0] = __builtin_amdgcn_mfma_f32_16x16x32_bf16(af, b0, acc[0], 0, 0, 0);
        acc[1] = __builtin_amdgcn_mfma_f32_16x16x32_bf16(af, b1, acc[1], 0, 0, 0);

        ++buf; if (buf == 3) buf = 0;
    }

    // logits -> LDS: row = wave*16 + (lane>>4)*4 + j, col = n*16 + rsel
    const int r0 = wave * 16 + ((lane >> 4) << 2);
#pragma unroll
    for (int n = 0; n < 2; ++n) {
        const int c = n * 16 + rsel;
        if (c < 21) {
#pragma unroll
            for (int j = 0; j < 4; ++j)
                sS[r0 + j][c] = acc[n][j];
        }
    }
    __syncthreads();

    if (tid < 64) {
        float mx = -1e30f;
#pragma unroll
        for (int l = 0; l < Ld; ++l) mx = fmaxf(mx, sS[tid][l]);
        float e[Ld]; float sum = 0.f;
#pragma unroll
        for (int l = 0; l < Ld; ++l) { e[l] = __expf(sS[tid][l] - mx); sum += e[l]; }
        const float inv = 1.f / sum;
        const int grow = m0 + tid;
#pragma unroll
        for (int l = 0; l < Ld; ++l)
            att[(size_t)grow * Ld + l] = e[l] * inv;
    }
}

// ---------------------------------------------------------------------------
// out[row][d] = x[row][d] + sum_i att[row][i] * p1[row-i][d]
// 8 rows/block (wave per row); XCD-chunked so each XCD's p1 window fits L2.
// ---------------------------------------------------------------------------
__global__ __launch_bounds__(512) void out_kernel(
    const float* __restrict__ x, const unsigned short* __restrict__ p1,
    const float* __restrict__ att, float* __restrict__ out)
{
    const int bid = blockIdx.x;                       // 3000
    const int nid = (bid & 7) * 375 + (bid >> 3);     // XCD-contiguous chunks
    const int wave = threadIdx.x >> 6;
    const int lane = threadIdx.x & 63;
    const int row  = nid * 8 + wave;
    const int t    = row % Td;
    const int d0   = lane * 8;

    float av[Ld];
    const float* ar = att + (size_t)row * Ld;
#pragma unroll
    for (int i = 0; i < Ld; i += 4) {
        float4 v = *(const float4*)(ar + i);
        av[i] = v.x; av[i + 1] = v.y; av[i + 2] = v.z; av[i + 3] = v.w;
    }

    const float* xr = x + (size_t)row * Dd + d0;
    float4 xa = *(const float4*)xr;
    float4 xb4 = *(const float4*)(xr + 4);
    float acc[8] = { xa.x, xa.y, xa.z, xa.w, xb4.x, xb4.y, xb4.z, xb4.w };

    const int imax = (t < Ld - 1) ? t : (Ld - 1);
    const unsigned short* pr = p1 + (size_t)row * Dd + d0;
    for (int i = 0; i <= imax; ++i) {
        const float a = av[i];
        short8 p = *(const short8*)(pr - (size_t)i * Dd);
#pragma unroll
        for (int j = 0; j < 8; ++j) acc[j] += a * bf2f((unsigned short)p[j]);
    }
    float* orow = out + (size_t)row * Dd + d0;
    float4 o0 = { acc[0], acc[1], acc[2], acc[3] };
    float4 o1 = { acc[4], acc[5], acc[6], acc[7] };
    *(float4*)orow       = o0;
    *(float4*)(orow + 4) = o1;
}

// ---------------------------------------------------------------------------
extern "C" void kernel_launch(void* const* d_in, const int* in_sizes, int n_in,
                              void* d_out, int out_size, void* d_ws, size_t ws_size,
                              hipStream_t stream)
{
    const float* x  = (const float*)d_in[0];
    const float* w1 = (const float*)d_in[1];
    const float* b1 = (const float*)d_in[2];
    const float* wp = (const float*)d_in[3];
    const float* wa = (const float*)d_in[4];
    float* out = (float*)d_out;

    char* ws = (char*)d_ws;
    unsigned short* xb  = (unsigned short*)ws;  ws += (size_t)Md * Dd * 2;   // bf16 x
    unsigned short* w1T = (unsigned short*)ws;  ws += (size_t)Hd * Dd * 2;
    unsigned short* wpT = (unsigned short*)ws;  ws += (size_t)Dd * Hd * 2;
    unsigned short* waT = (unsigned short*)ws;  ws += (size_t)32 * Dd * 2;
    unsigned short* f1  = (unsigned short*)ws;  ws += (size_t)Md * Hd * 2;
    unsigned short* p1  = (unsigned short*)ws;  ws += (size_t)Md * Dd * 2;
    float*          att = (float*)ws;           ws += (size_t)Md * Ld * 4;

    prep_kernel<<<7088, 256, 0, stream>>>(x, w1, wp, wa, xb, w1T, wpT, waT);

    att_mfma_kernel<<<Md / 64, 256, 0, stream>>>(xb, waT, att);

    const int mtiles = (Md + 255) / 256;   // 94
    gemm_lds<true ><<<dim3(Hd / 128, mtiles), 512, 0, stream>>>(xb, w1T, b1, f1, Md, Hd, Dd);
    gemm_lds<false><<<dim3(Dd / 128, mtiles), 512, 0, stream>>>(f1, wpT, nullptr, p1, Md, Dd, Hd);

    out_kernel<<<Md / 8, 512, 0, stream>>>(x, p1, att, out);
}